// Round 13
// baseline (368.549 us; speedup 1.0000x reference)
//
#include <hip/hip_runtime.h>
#include <hip/hip_bf16.h>

#define BB   131072
#define CC   16
#define DIN  256
#define DH   1024
#define DOUT 256
#define TM   64    // tokens per tile
#define NHB  32    // hidden blocks of 32
#define NB   512   // bucketing blocks (BB/NB = 256 tokens each)

typedef __attribute__((ext_vector_type(8))) short bf16x8;
typedef __attribute__((ext_vector_type(4))) short short4v;
typedef __attribute__((ext_vector_type(4))) float f32x4;

__device__ inline unsigned short f2b(float f) {
  union { float f; unsigned u; } v; v.f = f;
  unsigned u = v.u;
  return (unsigned short)((u + 0x7fffu + ((u >> 16) & 1u)) >> 16);  // RNE
}

__device__ inline void gload_lds16(const void* g, void* l) {
  __builtin_amdgcn_global_load_lds(
      (const __attribute__((address_space(1))) void*)g,
      (__attribute__((address_space(3))) void*)l, 16, 0, 0);
}

#define MFMA16(a, b, c) __builtin_amdgcn_mfma_f32_16x16x32_bf16((a), (b), (c), 0, 0, 0)

// ---------------- bucketing (contention-free counting sort) ----------------
__global__ void hist_k(const int* __restrict__ cat, int* __restrict__ blockhist) {
  __shared__ int h[CC];
  const int tid = threadIdx.x;
  if (tid < CC) h[tid] = 0;
  __syncthreads();
  const int i = blockIdx.x * 256 + tid;
  atomicAdd(&h[cat[i]], 1);
  __syncthreads();
  if (tid < CC) blockhist[blockIdx.x * CC + tid] = h[tid];
}

__global__ void offsets2_k(const int* __restrict__ blockhist,
                           int* __restrict__ counts, int* __restrict__ padoff,
                           int* __restrict__ base) {
  __shared__ int part[CC][64];
  __shared__ int pref[CC][64];
  __shared__ int scnt[CC];
  __shared__ int spad[CC + 1];
  const int tid = threadIdx.x;       // 1024 threads
  const int c = tid >> 6;
  const int g = tid & 63;
  int h[8];
  int s = 0;
#pragma unroll
  for (int i = 0; i < 8; i++) {
    h[i] = blockhist[(g * 8 + i) * CC + c];
    s += h[i];
  }
  part[c][g] = s;
  __syncthreads();
  if (g == 0) {
    int r = 0;
    for (int j = 0; j < 64; j++) { pref[c][j] = r; r += part[c][j]; }
    scnt[c] = r;
  }
  __syncthreads();
  if (tid == 0) {
    int acc = 0;
    for (int c2 = 0; c2 < CC; c2++) {
      spad[c2] = acc;
      padoff[c2] = acc;
      counts[c2] = scnt[c2];
      acc += ((scnt[c2] + TM - 1) / TM) * TM;
    }
    spad[CC] = acc;
    padoff[CC] = acc;
  }
  __syncthreads();
  int run = spad[c] + pref[c][g];
#pragma unroll
  for (int i = 0; i < 8; i++) {
    base[(g * 8 + i) * CC + c] = run;
    run += h[i];
  }
}

__global__ void scatter2_k(const int* __restrict__ cat, const int* __restrict__ base,
                           int* __restrict__ idx) {
  __shared__ int cur[CC];
  const int tid = threadIdx.x;
  if (tid < CC) cur[tid] = base[blockIdx.x * CC + tid];
  __syncthreads();
  const int i = blockIdx.x * 256 + tid;
  const int c = cat[i];
  const int pos = atomicAdd(&cur[c], 1);
  idx[pos] = i;
}

// -------- weight conversion: f32 -> bf16 in MFMA A-fragment order --------
// A-frag map (verified r1-r12): 16(row)x32(k) tile, lane = (row&15)+16*((k&31)>>3),
// byte j = (k&7)*2. Tiles stored [tile][lane][16B] = 1024 B.
// W1: per category [hb=32][nt=2][ks=8][lane][16B]  (16 KB per hb of 32 n)
__global__ void conv_w1_k(const float* __restrict__ W1, short* __restrict__ w1b) {
  int t = blockIdx.x * blockDim.x + threadIdx.x;   // 524288
  int n  = t & 1023;
  int j8 = (t >> 10) & 31;   // k-chunk of 8
  int c  = t >> 15;
  const float* src = W1 + (size_t)c * DIN * DH;
  bf16x8 o;
#pragma unroll
  for (int i = 0; i < 8; i++)
    o[i] = (short)f2b(src[(size_t)(j8 * 8 + i) * DH + n]);
  char* dst = (char*)w1b + (size_t)c * 524288
            + (n >> 5) * 16384 + ((n >> 4) & 1) * 8192 + (j8 >> 2) * 1024
            + ((n & 15) + 16 * (j8 & 3)) * 16;
  *(bf16x8*)dst = o;
}

// W2: per category [kb=32][nt=16][lane][16B]  (16 KB per k-block of 32)
__global__ void conv_w2_k(const float* __restrict__ W2, short* __restrict__ w2b) {
  int t = blockIdx.x * blockDim.x + threadIdx.x;   // 524288
  int n  = t & 255;
  int j8 = (t >> 8) & 127;   // k-chunk of 8 (k = hidden)
  int c  = t >> 15;
  const float* src = W2 + (size_t)c * DH * DOUT;
  bf16x8 o;
#pragma unroll
  for (int i = 0; i < 8; i++)
    o[i] = (short)f2b(src[(size_t)(j8 * 8 + i) * DOUT + n]);
  char* dst = (char*)w2b + (size_t)c * 524288
            + (j8 >> 2) * 16384 + (n >> 4) * 1024
            + ((n & 15) + 16 * (j8 & 3)) * 16;
  *(bf16x8*)dst = o;
}

// ---------------- fused routed MLP ----------------
// 256 thr = 4 waves = wt(2: token-tile pair) x wh(2). Tile = 64 tokens.
// w1: double-buffered LDS (staged at A-start, full A+B latency cover).
// w2: read DIRECTLY from L2-resident frag-order global array in region B
//     (1KB/wave coalesced; removes w2 staging-writes AND LDS reads).
// Schedule per hb: A{stage1(hb+1); L1 8 ds_read -> 16 MFMA; relu->hs; lgkm(0)+bar}
//                  B{2 hs ds_read; 8 w2 global loads -> 16 MFMA; vmcnt(0)+bar}
// LDS: w1 dbuf 2x16K @0 | hs 4K @32K | toks | b1s | b2s  (42240 B, 3 blocks/CU)
#define HSOFF  32768
#define TKOFF  36864
#define B1OFF  37120
#define B2OFF  41216
#define SMSZ   42240

__launch_bounds__(256, 3)
__global__ void mlp_k(const float* __restrict__ x,
                      const float* __restrict__ b1,
                      const float* __restrict__ b2,
                      const short* __restrict__ w1b,
                      const short* __restrict__ w2b,
                      const int* __restrict__ idx,
                      const int* __restrict__ padoff,
                      const int* __restrict__ counts,
                      float* __restrict__ out) {
  __shared__ __align__(16) char sm[SMSZ];

  const int bhw = blockIdx.x;
  const int wg = (bhw & 7) * 258 + (bhw >> 3);   // XCD-chunked swizzle, 2064 = 8*258
  const int p = wg * TM;
  const int total = padoff[CC];
  if (p >= total) return;
  int c = 0;
  while (padoff[c + 1] <= p) c++;
  const int cnt = counts[c];
  const int start = p - padoff[c];

  const int tid  = threadIdx.x;
  const int lane = tid & 63;
  const int w    = tid >> 6;   // 0..3
  const int wt   = w >> 1;     // 0..1: token-tile pair {2wt, 2wt+1}
  const int wh   = w & 1;      // L1: n-half of 32; L2: out-half of 256
  const int lrow = lane & 15;
  const int lgrp = lane >> 4;

  char*  hsb   = sm + HSOFF;
  int*   toksp = (int*)(sm + TKOFF);
  float* b1s   = (float*)(sm + B1OFF);
  float* b2s   = (float*)(sm + B2OFF);

  // ---- prologue: gather x, f32->bf16, B-frag order [tt=4][ks=8][lane][16B] ----
  // xs occupies sm[0,32K) = w1 dbuf region (freed before staging starts)
  {
    const int r = tid >> 2;      // 0..63 token slot
    const int q = tid & 3;       // 64-float quarter
    const int pos = start + r;
    int tok = (pos < cnt) ? idx[p + r] : -1;
    if (q == 0) toksp[r] = tok;
    char* tb = sm + (r >> 4) * 8192 + (r & 15) * 16;
    if (tok >= 0) {
      const f32x4* src = (const f32x4*)(x + (size_t)tok * DIN) + q * 16;
#pragma unroll
      for (int t = 0; t < 8; t++) {
        f32x4 v0 = src[2 * t];
        f32x4 v1 = src[2 * t + 1];
        bf16x8 o;
        o[0] = (short)f2b(v0[0]); o[1] = (short)f2b(v0[1]);
        o[2] = (short)f2b(v0[2]); o[3] = (short)f2b(v0[3]);
        o[4] = (short)f2b(v1[0]); o[5] = (short)f2b(v1[1]);
        o[6] = (short)f2b(v1[2]); o[7] = (short)f2b(v1[3]);
        *(bf16x8*)(tb + (2 * q + (t >> 2)) * 1024 + (t & 3) * 256) = o;
      }
    } else {
      bf16x8 z = {0, 0, 0, 0, 0, 0, 0, 0};
#pragma unroll
      for (int t = 0; t < 8; t++)
        *(bf16x8*)(tb + (2 * q + (t >> 2)) * 1024 + (t & 3) * 256) = z;
    }
    ((f32x4*)b1s)[tid] = ((const f32x4*)(b1 + (size_t)c * DH))[tid];
    if (tid < 64) ((f32x4*)b2s)[tid] = ((const f32x4*)(b2 + (size_t)c * DOUT))[tid];
  }
  __syncthreads();

  // ---- x fragments to registers: 2 token tiles ----
  bf16x8 xf[2][8];
#pragma unroll
  for (int ti = 0; ti < 2; ti++)
#pragma unroll
    for (int ks = 0; ks < 8; ks++)
      xf[ti][ks] = *(const bf16x8*)(sm + (2 * wt + ti) * 8192 + ks * 1024 + lane * 16);
  __syncthreads();   // xs region free -> w1 double buffer

  const char* w1g = (const char*)w1b + (size_t)c * 524288;
  const char* w2g = (const char*)w2b + (size_t)c * 524288;

  auto stage1 = [&](int i) {   // 16 KB linear into buf (i&1), 4 vm ops/thread
    const char* src = w1g + (size_t)i * 16384;
    char* dst = sm + (i & 1) * 16384;
#pragma unroll
    for (int j = 0; j < 4; j++) {
      int chunk = (w * 4 + j) * 1024;
      gload_lds16(src + chunk + lane * 16, dst + chunk);
    }
  };

  stage1(0);
  asm volatile("s_waitcnt vmcnt(0)" ::: "memory");
  __syncthreads();   // w1[0] ready

  f32x4 acc2[2][8];   // [token tile][out tile]
#pragma unroll
  for (int ti = 0; ti < 2; ti++)
#pragma unroll
    for (int ni = 0; ni < 8; ni++)
      acc2[ti][ni] = (f32x4){0.f, 0.f, 0.f, 0.f};

  // hs write position (D-frag -> B-frag order), constant per thread:
  const int hswr = (lrow + 16 * (wh * 2 + (lgrp >> 1))) * 16 + (lgrp & 1) * 8;

  for (int hb = 0; hb < NHB; hb++) {
    const bool notlast = (hb < NHB - 1);
    const char* w1c = sm + (hb & 1) * 16384 + wh * 8192;

    // ===== region A: issue stage1(hb+1) into buf^1; L1 (8 ds_read -> 16 MFMA);
    //                 relu -> hs; lgkm(0)+barrier (vmcnt NOT drained here) =====
    if (notlast) stage1(hb + 1);

    f32x4 p0 = (f32x4){0.f, 0.f, 0.f, 0.f};
    f32x4 p1 = (f32x4){0.f, 0.f, 0.f, 0.f};
    __builtin_amdgcn_s_setprio(1);
#pragma unroll
    for (int ks = 0; ks < 8; ks++) {
      bf16x8 a = *(const bf16x8*)(w1c + ks * 1024 + lane * 16);
      p0 = MFMA16(a, xf[0][ks], p0);
      p1 = MFMA16(a, xf[1][ks], p1);
    }
    __builtin_amdgcn_s_setprio(0);

    {
      f32x4 bv = *(const f32x4*)(b1s + hb * 32 + wh * 16 + lgrp * 4);
      short4v h0, h1;
#pragma unroll
      for (int jj = 0; jj < 4; jj++) {
        h0[jj] = (short)f2b(fmaxf(p0[jj] + bv[jj], 0.0f));
        h1[jj] = (short)f2b(fmaxf(p1[jj] + bv[jj], 0.0f));
      }
      *(short4v*)(hsb + (2 * wt) * 1024 + hswr)     = h0;
      *(short4v*)(hsb + (2 * wt + 1) * 1024 + hswr) = h1;
    }
    asm volatile("s_waitcnt lgkmcnt(0)" ::: "memory");   // publish hs only
    __builtin_amdgcn_s_barrier();

    // ===== region B: L2 from hs (LDS) x w2 (direct L2 global) =====
    {
      const char* w2r = w2g + (size_t)hb * 16384 + (wh * 8) * 1024 + lane * 16;
      bf16x8 hf0 = *(const bf16x8*)(hsb + (2 * wt) * 1024 + lane * 16);
      bf16x8 hf1 = *(const bf16x8*)(hsb + (2 * wt + 1) * 1024 + lane * 16);
      __builtin_amdgcn_s_setprio(1);
#pragma unroll
      for (int ni = 0; ni < 8; ni++) {
        bf16x8 a2 = *(const bf16x8*)(w2r + ni * 1024);   // global, L2-hot, coalesced
        acc2[0][ni] = MFMA16(a2, hf0, acc2[0][ni]);
        acc2[1][ni] = MFMA16(a2, hf1, acc2[1][ni]);
      }
      __builtin_amdgcn_s_setprio(0);
    }
    // w1[hb+1] landed (stage1 got full A+B cover; w2 loads already consumed);
    // hs reads drained before next region rewrites it
    if (notlast) {
      asm volatile("s_waitcnt vmcnt(0) lgkmcnt(0)" ::: "memory");
      __builtin_amdgcn_s_barrier();
    }
  }

  // ---- epilogue: + b2, vectorized scatter ----
#pragma unroll
  for (int ti = 0; ti < 2; ti++) {
    const int tok = toksp[(2 * wt + ti) * 16 + lrow];
    if (tok >= 0) {
#pragma unroll
      for (int ni = 0; ni < 8; ni++) {
        const int n0 = wh * 128 + ni * 16 + lgrp * 4;
        f32x4 bv = *(const f32x4*)(b2s + n0);
        f32x4 v = acc2[ti][ni] + bv;
        *(f32x4*)(out + (size_t)tok * DOUT + n0) = v;
      }
    }
  }
}

extern "C" void kernel_launch(void* const* d_in, const int* in_sizes, int n_in,
                              void* d_out, int out_size, void* d_ws, size_t ws_size,
                              hipStream_t stream) {
  (void)in_sizes; (void)n_in; (void)out_size; (void)ws_size;
  const float* x   = (const float*)d_in[0];
  const int*   cat = (const int*)d_in[1];
  const float* W1  = (const float*)d_in[2];
  const float* b1  = (const float*)d_in[3];
  const float* W2  = (const float*)d_in[4];
  const float* b2  = (const float*)d_in[5];
  float* out = (float*)d_out;

  char* ws = (char*)d_ws;
  int* counts    = (int*)(ws);
  int* padoff    = (int*)(ws + 128);
  int* blockhist = (int*)(ws + 4096);
  int* base      = (int*)(ws + 65536);
  int* idx       = (int*)(ws + 131072);
  short* w1b     = (short*)(ws + (1 << 20));
  short* w2b     = (short*)(ws + (1 << 20) + 8388608);

  hist_k<<<NB, 256, 0, stream>>>(cat, blockhist);
  offsets2_k<<<1, 1024, 0, stream>>>(blockhist, counts, padoff, base);
  scatter2_k<<<NB, 256, 0, stream>>>(cat, base, idx);
  conv_w1_k<<<2048, 256, 0, stream>>>(W1, w1b);
  conv_w2_k<<<2048, 256, 0, stream>>>(W2, w2b);

  const int ntiles = BB / TM + CC;   // 2064 = 8 * 258 (swizzle assumes this)
  mlp_k<<<ntiles, 256, 0, stream>>>(x, b1, b2, w1b, w2b, idx, padoff, counts, out);
}

// Round 14
// 299.148 us; speedup vs baseline: 1.2320x; 1.2320x over previous
//
#include <hip/hip_runtime.h>
#include <hip/hip_bf16.h>

#define BB   131072
#define CC   16
#define DIN  256
#define DH   1024
#define DOUT 256
#define NB   512   // bucketing blocks (BB/NB = 256 tokens each)

typedef __attribute__((ext_vector_type(8))) short bf16x8;
typedef __attribute__((ext_vector_type(4))) short short4v;
typedef __attribute__((ext_vector_type(4))) float f32x4;

__device__ inline unsigned short f2b(float f) {
  union { float f; unsigned u; } v; v.f = f;
  unsigned u = v.u;
  return (unsigned short)((u + 0x7fffu + ((u >> 16) & 1u)) >> 16);  // RNE
}

__device__ inline void gload_lds16(const void* g, void* l) {
  __builtin_amdgcn_global_load_lds(
      (const __attribute__((address_space(1))) void*)g,
      (__attribute__((address_space(3))) void*)l, 16, 0, 0);
}

#define MFMA16(a, b, c) __builtin_amdgcn_mfma_f32_16x16x32_bf16((a), (b), (c), 0, 0, 0)

// ---------------- bucketing (contention-free counting sort) ----------------
__global__ void hist_k(const int* __restrict__ cat, int* __restrict__ blockhist) {
  __shared__ int h[CC];
  const int tid = threadIdx.x;
  if (tid < CC) h[tid] = 0;
  __syncthreads();
  const int i = blockIdx.x * 256 + tid;
  atomicAdd(&h[cat[i]], 1);
  __syncthreads();
  if (tid < CC) blockhist[blockIdx.x * CC + tid] = h[tid];
}

__global__ void offsets2_k(const int* __restrict__ blockhist,
                           int* __restrict__ counts, int* __restrict__ padoff,
                           int* __restrict__ base, int tm) {
  __shared__ int part[CC][64];
  __shared__ int pref[CC][64];
  __shared__ int scnt[CC];
  __shared__ int spad[CC + 1];
  const int tid = threadIdx.x;       // 1024 threads
  const int c = tid >> 6;
  const int g = tid & 63;
  int h[8];
  int s = 0;
#pragma unroll
  for (int i = 0; i < 8; i++) {
    h[i] = blockhist[(g * 8 + i) * CC + c];
    s += h[i];
  }
  part[c][g] = s;
  __syncthreads();
  if (g == 0) {
    int r = 0;
    for (int j = 0; j < 64; j++) { pref[c][j] = r; r += part[c][j]; }
    scnt[c] = r;
  }
  __syncthreads();
  if (tid == 0) {
    int acc = 0;
    for (int c2 = 0; c2 < CC; c2++) {
      spad[c2] = acc;
      padoff[c2] = acc;
      counts[c2] = scnt[c2];
      acc += ((scnt[c2] + tm - 1) / tm) * tm;
    }
    spad[CC] = acc;
    padoff[CC] = acc;
  }
  __syncthreads();
  int run = spad[c] + pref[c][g];
#pragma unroll
  for (int i = 0; i < 8; i++) {
    base[(g * 8 + i) * CC + c] = run;
    run += h[i];
  }
}

__global__ void scatter2_k(const int* __restrict__ cat, const int* __restrict__ base,
                           int* __restrict__ idx) {
  __shared__ int cur[CC];
  const int tid = threadIdx.x;
  if (tid < CC) cur[tid] = base[blockIdx.x * CC + tid];
  __syncthreads();
  const int i = blockIdx.x * 256 + tid;
  const int c = cat[i];
  const int pos = atomicAdd(&cur[c], 1);
  idx[pos] = i;
}

// -------- weight conversion: f32 -> bf16 in MFMA A-fragment order --------
// A-frag map (verified r1-r13): 16(row)x32(k) tile, lane = (row&15)+16*((k&31)>>3),
// byte j = (k&7)*2. Tiles stored [tile][lane][16B] = 1024 B.
// W1: per category [nt = n>>4][ks = k>>5][lane][16B]   (8 KB per 16-n tile)
__global__ void conv_w1_k(const float* __restrict__ W1, short* __restrict__ w1b) {
  int t = blockIdx.x * blockDim.x + threadIdx.x;   // 524288
  int n  = t & 1023;
  int j8 = (t >> 10) & 31;   // k-chunk of 8
  int c  = t >> 15;
  const float* src = W1 + (size_t)c * DIN * DH;
  bf16x8 o;
#pragma unroll
  for (int i = 0; i < 8; i++)
    o[i] = (short)f2b(src[(size_t)(j8 * 8 + i) * DH + n]);
  char* dst = (char*)w1b + (size_t)c * 524288
            + (n >> 4) * 8192 + (j8 >> 2) * 1024
            + ((n & 15) + 16 * (j8 & 3)) * 16;
  *(bf16x8*)dst = o;
}

// W2: per category [kb = k>>5][nt = n>>4][lane][16B]  (16 KB per 32-k block)
__global__ void conv_w2_k(const float* __restrict__ W2, short* __restrict__ w2b) {
  int t = blockIdx.x * blockDim.x + threadIdx.x;   // 524288
  int n  = t & 255;
  int j8 = (t >> 8) & 127;   // k-chunk of 8 (k = hidden)
  int c  = t >> 15;
  const float* src = W2 + (size_t)c * DH * DOUT;
  bf16x8 o;
#pragma unroll
  for (int i = 0; i < 8; i++)
    o[i] = (short)f2b(src[(size_t)(j8 * 8 + i) * DOUT + n]);
  char* dst = (char*)w2b + (size_t)c * 524288
            + (j8 >> 2) * 16384 + (n >> 4) * 1024
            + ((n & 15) + 16 * (j8 & 3)) * 16;
  *(bf16x8*)dst = o;
}

// ================= PASS 1: x -> hidden (bf16, B-frag order in HBM) =================
// 512 thr, 8 waves = wt(4 token-tile pairs) x wh(2 nt-pairs of 4). TM=128, HBLK=64.
// hidden layout: [tok-tile][kb=32][lane][16B] = 32 KB per 16 tokens.
// LDS: w1 dbuf 2x32K @0 (x prologue overlaps) | toks @64K | b1s @64.5K  (~68.8 KB)
#define P1TK   65536
#define P1B1   66048
#define P1SM   70144

__launch_bounds__(512, 4)
__global__ void p1_k(const float* __restrict__ x,
                     const float* __restrict__ b1,
                     const short* __restrict__ w1b,
                     const int* __restrict__ idx,
                     const int* __restrict__ padoff,
                     const int* __restrict__ counts,
                     char* __restrict__ hid) {
  __shared__ __align__(16) char sm[P1SM];

  const int bhw = blockIdx.x;
  const int wg = (bhw & 7) * 130 + (bhw >> 3);   // 1040 = 8*130
  const int p = wg * 128;
  const int total = padoff[CC];
  if (p >= total) return;
  int c = 0;
  while (padoff[c + 1] <= p) c++;
  const int cnt = counts[c];
  const int start = p - padoff[c];

  const int tid  = threadIdx.x;
  const int lane = tid & 63;
  const int w    = tid >> 6;   // 0..7
  const int wt   = w >> 1;     // token-tile pair {2wt, 2wt+1}
  const int wh   = w & 1;      // nt-pair {2wh, 2wh+1} of 4 per hb
  const int lrow = lane & 15;
  const int lgrp = lane >> 4;

  int*   toksp = (int*)(sm + P1TK);
  float* b1s   = (float*)(sm + P1B1);

  // ---- prologue: gather x, f32->bf16, B-frag order [tt=8][ks=8][lane][16B] ----
  {
    const int r = tid >> 2;      // 0..127
    const int q = tid & 3;
    const int pos = start + r;
    int tok = (pos < cnt) ? idx[p + r] : -1;
    if (q == 0) toksp[r] = tok;
    char* tb = sm + (r >> 4) * 8192 + (r & 15) * 16;
    if (tok >= 0) {
      const f32x4* src = (const f32x4*)(x + (size_t)tok * DIN) + q * 16;
#pragma unroll
      for (int t = 0; t < 8; t++) {
        f32x4 v0 = src[2 * t];
        f32x4 v1 = src[2 * t + 1];
        bf16x8 o;
        o[0] = (short)f2b(v0[0]); o[1] = (short)f2b(v0[1]);
        o[2] = (short)f2b(v0[2]); o[3] = (short)f2b(v0[3]);
        o[4] = (short)f2b(v1[0]); o[5] = (short)f2b(v1[1]);
        o[6] = (short)f2b(v1[2]); o[7] = (short)f2b(v1[3]);
        *(bf16x8*)(tb + (2 * q + (t >> 2)) * 1024 + (t & 3) * 256) = o;
      }
    } else {
      bf16x8 z = {0, 0, 0, 0, 0, 0, 0, 0};
#pragma unroll
      for (int t = 0; t < 8; t++)
        *(bf16x8*)(tb + (2 * q + (t >> 2)) * 1024 + (t & 3) * 256) = z;
    }
    if (tid < 256) ((f32x4*)b1s)[tid] = ((const f32x4*)(b1 + (size_t)c * DH))[tid];
  }
  __syncthreads();

  bf16x8 xf[2][8];
#pragma unroll
  for (int ti = 0; ti < 2; ti++)
#pragma unroll
    for (int ks = 0; ks < 8; ks++)
      xf[ti][ks] = *(const bf16x8*)(sm + (2 * wt + ti) * 8192 + ks * 1024 + lane * 16);
  __syncthreads();   // xs region free -> w1 dbuf

  const char* w1g = (const char*)w1b + (size_t)c * 524288;
  auto stage1 = [&](int i) {   // 32 KB linear, 4 vm ops/thread
    const char* src = w1g + (size_t)i * 32768;
    char* dst = sm + (i & 1) * 32768;
#pragma unroll
    for (int j = 0; j < 4; j++) {
      int chunk = (w * 4 + j) * 1024;
      gload_lds16(src + chunk + lane * 16, dst + chunk);
    }
  };

  stage1(0);
  asm volatile("s_waitcnt vmcnt(0)" ::: "memory");
  __syncthreads();

  // hidden write base for this wave's kb = hb*2 + wh
  const int hp = (lrow + 16 * (lgrp >> 1)) * 16 + (lgrp & 1) * 8;   // nj=0 position
  char* hb0 = hid + ((size_t)(wg * 8 + 2 * wt)) * 32768;
  char* hb1 = hid + ((size_t)(wg * 8 + 2 * wt + 1)) * 32768;

  for (int hb = 0; hb < 16; hb++) {
    const bool notlast = (hb < 15);
    const char* w1c = sm + (hb & 1) * 32768;
    if (notlast) stage1(hb + 1);

    f32x4 acc1[2][2];   // [ti][nj]
#pragma unroll
    for (int ti = 0; ti < 2; ti++)
#pragma unroll
      for (int nj = 0; nj < 2; nj++)
        acc1[ti][nj] = (f32x4){0.f, 0.f, 0.f, 0.f};

    __builtin_amdgcn_s_setprio(1);
#pragma unroll
    for (int ks = 0; ks < 8; ks++) {
      bf16x8 a0 = *(const bf16x8*)(w1c + (2 * wh + 0) * 8192 + ks * 1024 + lane * 16);
      bf16x8 a1 = *(const bf16x8*)(w1c + (2 * wh + 1) * 8192 + ks * 1024 + lane * 16);
      acc1[0][0] = MFMA16(a0, xf[0][ks], acc1[0][0]);
      acc1[1][0] = MFMA16(a0, xf[1][ks], acc1[1][0]);
      acc1[0][1] = MFMA16(a1, xf[0][ks], acc1[0][1]);
      acc1[1][1] = MFMA16(a1, xf[1][ks], acc1[1][1]);
    }
    __builtin_amdgcn_s_setprio(0);

    // bias+relu -> hidden (global, B-frag order), kb = hb*2 + wh
    const int kboff = (hb * 2 + wh) * 1024;
#pragma unroll
    for (int nj = 0; nj < 2; nj++) {
      f32x4 bv = *(const f32x4*)(b1s + hb * 64 + (2 * wh + nj) * 16 + lgrp * 4);
      short4v h0, h1;
#pragma unroll
      for (int jj = 0; jj < 4; jj++) {
        h0[jj] = (short)f2b(fmaxf(acc1[0][nj][jj] + bv[jj], 0.0f));
        h1[jj] = (short)f2b(fmaxf(acc1[1][nj][jj] + bv[jj], 0.0f));
      }
      *(short4v*)(hb0 + kboff + hp + nj * 512) = h0;
      *(short4v*)(hb1 + kboff + hp + nj * 512) = h1;
    }

    if (notlast) {
      // wait the 4 stage ops (oldest); the 4 stores keep flying
      asm volatile("s_waitcnt vmcnt(4)" ::: "memory");
      __builtin_amdgcn_s_barrier();
    }
  }
}

// ================= PASS 2: hidden -> out =================
// 512 thr, 8 waves = wt(4 pairs) x wh(2 out-halves). TM=128. 32 kb-steps of 32.
// hf streamed from HBM into register double-buffer; w2 dbuf in LDS.
// LDS: w2 dbuf 2x16K @0 | toks @32K | b2s  (~33.8 KB)
#define P2TK   32768
#define P2B2   33280
#define P2SM   34304

__launch_bounds__(512, 4)
__global__ void p2_k(const float* __restrict__ b2,
                     const short* __restrict__ w2b,
                     const int* __restrict__ idx,
                     const int* __restrict__ padoff,
                     const int* __restrict__ counts,
                     const char* __restrict__ hid,
                     float* __restrict__ out) {
  __shared__ __align__(16) char sm[P2SM];

  const int bhw = blockIdx.x;
  const int wg = (bhw & 7) * 130 + (bhw >> 3);   // 1040 = 8*130
  const int p = wg * 128;
  const int total = padoff[CC];
  if (p >= total) return;
  int c = 0;
  while (padoff[c + 1] <= p) c++;
  const int cnt = counts[c];
  const int start = p - padoff[c];

  const int tid  = threadIdx.x;
  const int lane = tid & 63;
  const int w    = tid >> 6;
  const int wt   = w >> 1;     // token-tile pair {2wt, 2wt+1}
  const int wh   = w & 1;      // out-half
  const int lrow = lane & 15;
  const int lgrp = lane >> 4;

  int*   toksp = (int*)(sm + P2TK);
  float* b2s   = (float*)(sm + P2B2);

  if (tid < 128) {
    const int pos = start + tid;
    toksp[tid] = (pos < cnt) ? idx[p + tid] : -1;
  }
  if (tid < 64) ((f32x4*)b2s)[tid] = ((const f32x4*)(b2 + (size_t)c * DOUT))[tid];

  const char* w2g = (const char*)w2b + (size_t)c * 524288;
  auto stage2 = [&](int i) {   // 16 KB linear, 2 vm ops/thread
    const char* src = w2g + (size_t)i * 16384;
    char* dst = sm + (i & 1) * 16384;
#pragma unroll
    for (int j = 0; j < 2; j++) {
      int chunk = (w * 2 + j) * 1024;
      gload_lds16(src + chunk + lane * 16, dst + chunk);
    }
  };

  const char* h0 = hid + ((size_t)(wg * 8 + 2 * wt)) * 32768 + lane * 16;
  const char* h1 = hid + ((size_t)(wg * 8 + 2 * wt + 1)) * 32768 + lane * 16;

  f32x4 acc2[2][8];
#pragma unroll
  for (int ti = 0; ti < 2; ti++)
#pragma unroll
    for (int ni = 0; ni < 8; ni++)
      acc2[ti][ni] = (f32x4){0.f, 0.f, 0.f, 0.f};

  __syncthreads();          // toks/b2s ready (before staging into sm[0..32K))
  stage2(0);
  bf16x8 hfA0 = *(const bf16x8*)(h0);
  bf16x8 hfA1 = *(const bf16x8*)(h1);
  asm volatile("s_waitcnt vmcnt(0)" ::: "memory");
  __builtin_amdgcn_s_barrier();

  bf16x8 hfB0, hfB1;
#pragma unroll
  for (int kb = 0; kb < 32; kb += 2) {
    // even: consume A (w2 buf 0), prefetch kb+1 -> B
    {
      stage2(kb + 1);
      hfB0 = *(const bf16x8*)(h0 + (kb + 1) * 1024);
      hfB1 = *(const bf16x8*)(h1 + (kb + 1) * 1024);
      const char* w2c = sm;   // buf 0
      __builtin_amdgcn_s_setprio(1);
#pragma unroll
      for (int ni = 0; ni < 8; ni++) {
        bf16x8 a2 = *(const bf16x8*)(w2c + (wh * 8 + ni) * 1024 + lane * 16);
        acc2[0][ni] = MFMA16(a2, hfA0, acc2[0][ni]);
        acc2[1][ni] = MFMA16(a2, hfA1, acc2[1][ni]);
      }
      __builtin_amdgcn_s_setprio(0);
      asm volatile("s_waitcnt vmcnt(0) lgkmcnt(0)" ::: "memory");
      __builtin_amdgcn_s_barrier();
    }
    // odd: consume B (w2 buf 1), prefetch kb+2 -> A
    {
      const bool more = (kb + 2 < 32);
      if (more) {
        stage2(kb + 2);
        hfA0 = *(const bf16x8*)(h0 + (kb + 2) * 1024);
        hfA1 = *(const bf16x8*)(h1 + (kb + 2) * 1024);
      }
      const char* w2c = sm + 16384;   // buf 1
      __builtin_amdgcn_s_setprio(1);
#pragma unroll
      for (int ni = 0; ni < 8; ni++) {
        bf16x8 a2 = *(const bf16x8*)(w2c + (wh * 8 + ni) * 1024 + lane * 16);
        acc2[0][ni] = MFMA16(a2, hfB0, acc2[0][ni]);
        acc2[1][ni] = MFMA16(a2, hfB1, acc2[1][ni]);
      }
      __builtin_amdgcn_s_setprio(0);
      if (more) {
        asm volatile("s_waitcnt vmcnt(0) lgkmcnt(0)" ::: "memory");
        __builtin_amdgcn_s_barrier();
      }
    }
  }

  // ---- epilogue: + b2, vectorized scatter ----
#pragma unroll
  for (int ti = 0; ti < 2; ti++) {
    const int tok = toksp[(2 * wt + ti) * 16 + lrow];
    if (tok >= 0) {
#pragma unroll
      for (int ni = 0; ni < 8; ni++) {
        const int n0 = wh * 128 + ni * 16 + lgrp * 4;
        f32x4 bv = *(const f32x4*)(b2s + n0);
        f32x4 v = acc2[ti][ni] + bv;
        *(f32x4*)(out + (size_t)tok * DOUT + n0) = v;
      }
    }
  }
}

// ================= FALLBACK: fused r12 kernel (218 us verified) =================
#define FTM   64
#define FW2   16384
#define FHS   32768
#define FTK   36864
#define FB1   37120
#define FB2   41216
#define FSM   42240

__launch_bounds__(256, 3)
__global__ void mlp_k(const float* __restrict__ x,
                      const float* __restrict__ b1,
                      const float* __restrict__ b2,
                      const short* __restrict__ w1b,
                      const short* __restrict__ w2b,
                      const int* __restrict__ idx,
                      const int* __restrict__ padoff,
                      const int* __restrict__ counts,
                      float* __restrict__ out) {
  __shared__ __align__(16) char sm[FSM];

  const int bhw = blockIdx.x;
  const int wg = (bhw & 7) * 258 + (bhw >> 3);   // 2064 = 8*258
  const int p = wg * FTM;
  const int total = padoff[CC];
  if (p >= total) return;
  int c = 0;
  while (padoff[c + 1] <= p) c++;
  const int cnt = counts[c];
  const int start = p - padoff[c];

  const int tid  = threadIdx.x;
  const int lane = tid & 63;
  const int w    = tid >> 6;
  const int wt   = w >> 1;
  const int wh   = w & 1;
  const int lrow = lane & 15;
  const int lgrp = lane >> 4;

  char*  hsb   = sm + FHS;
  int*   toksp = (int*)(sm + FTK);
  float* b1s   = (float*)(sm + FB1);
  float* b2s   = (float*)(sm + FB2);

  {
    const int r = tid >> 2;
    const int q = tid & 3;
    const int pos = start + r;
    int tok = (pos < cnt) ? idx[p + r] : -1;
    if (q == 0) toksp[r] = tok;
    char* tb = sm + (r >> 4) * 8192 + (r & 15) * 16;
    if (tok >= 0) {
      const f32x4* src = (const f32x4*)(x + (size_t)tok * DIN) + q * 16;
#pragma unroll
      for (int t = 0; t < 8; t++) {
        f32x4 v0 = src[2 * t];
        f32x4 v1 = src[2 * t + 1];
        bf16x8 o;
        o[0] = (short)f2b(v0[0]); o[1] = (short)f2b(v0[1]);
        o[2] = (short)f2b(v0[2]); o[3] = (short)f2b(v0[3]);
        o[4] = (short)f2b(v1[0]); o[5] = (short)f2b(v1[1]);
        o[6] = (short)f2b(v1[2]); o[7] = (short)f2b(v1[3]);
        *(bf16x8*)(tb + (2 * q + (t >> 2)) * 1024 + (t & 3) * 256) = o;
      }
    } else {
      bf16x8 z = {0, 0, 0, 0, 0, 0, 0, 0};
#pragma unroll
      for (int t = 0; t < 8; t++)
        *(bf16x8*)(tb + (2 * q + (t >> 2)) * 1024 + (t & 3) * 256) = z;
    }
    ((f32x4*)b1s)[tid] = ((const f32x4*)(b1 + (size_t)c * DH))[tid];
    if (tid < 64) ((f32x4*)b2s)[tid] = ((const f32x4*)(b2 + (size_t)c * DOUT))[tid];
  }
  __syncthreads();

  bf16x8 xf[2][8];
#pragma unroll
  for (int ti = 0; ti < 2; ti++)
#pragma unroll
    for (int ks = 0; ks < 8; ks++)
      xf[ti][ks] = *(const bf16x8*)(sm + (2 * wt + ti) * 8192 + ks * 1024 + lane * 16);
  __syncthreads();

  // fallback uses r12's [hb32][nt2] w1 view: offset (n>>4)*8192 == hb*16384 + nt*8192
  const char* w1g = (const char*)w1b + (size_t)c * 524288;
  const char* w2g = (const char*)w2b + (size_t)c * 524288;

  auto stage1 = [&](int i) {
    const char* src = w1g + (size_t)i * 16384;
#pragma unroll
    for (int j = 0; j < 4; j++) {
      int chunk = (w * 4 + j) * 1024;
      gload_lds16(src + chunk + lane * 16, sm + chunk);
    }
  };
  auto stage2 = [&](int i) {
    const char* src = w2g + (size_t)i * 16384;
#pragma unroll
    for (int j = 0; j < 4; j++) {
      int chunk = (w * 4 + j) * 1024;
      gload_lds16(src + chunk + lane * 16, sm + FW2 + chunk);
    }
  };

  stage1(0);
  asm volatile("s_waitcnt vmcnt(0)" ::: "memory");
  __syncthreads();

  f32x4 acc2[2][8];
#pragma unroll
  for (int ti = 0; ti < 2; ti++)
#pragma unroll
    for (int ni = 0; ni < 8; ni++)
      acc2[ti][ni] = (f32x4){0.f, 0.f, 0.f, 0.f};

  const int hswr = (lrow + 16 * (wh * 2 + (lgrp >> 1))) * 16 + (lgrp & 1) * 8;
  const char* w1c = sm + wh * 8192;
  const char* w2c = sm + FW2;

  for (int hb = 0; hb < 32; hb++) {
    const bool notlast = (hb < 31);
    stage2(hb);

    f32x4 p0 = (f32x4){0.f, 0.f, 0.f, 0.f};
    f32x4 p1 = (f32x4){0.f, 0.f, 0.f, 0.f};
    __builtin_amdgcn_s_setprio(1);
#pragma unroll
    for (int ks = 0; ks < 8; ks++) {
      bf16x8 a = *(const bf16x8*)(w1c + ks * 1024 + lane * 16);
      p0 = MFMA16(a, xf[0][ks], p0);
      p1 = MFMA16(a, xf[1][ks], p1);
    }
    __builtin_amdgcn_s_setprio(0);

    {
      f32x4 bv = *(const f32x4*)(b1s + hb * 32 + wh * 16 + lgrp * 4);
      short4v h0, h1;
#pragma unroll
      for (int jj = 0; jj < 4; jj++) {
        h0[jj] = (short)f2b(fmaxf(p0[jj] + bv[jj], 0.0f));
        h1[jj] = (short)f2b(fmaxf(p1[jj] + bv[jj], 0.0f));
      }
      *(short4v*)(hsb + (2 * wt) * 1024 + hswr)     = h0;
      *(short4v*)(hsb + (2 * wt + 1) * 1024 + hswr) = h1;
    }
    asm volatile("s_waitcnt vmcnt(0) lgkmcnt(0)" ::: "memory");
    __builtin_amdgcn_s_barrier();

    if (notlast) stage1(hb + 1);
    {
      bf16x8 hf0 = *(const bf16x8*)(hsb + (2 * wt) * 1024 + lane * 16);
      bf16x8 hf1 = *(const bf16x8*)(hsb + (2 * wt + 1) * 1024 + lane * 16);
      __builtin_amdgcn_s_setprio(1);
#pragma unroll
      for (int ni = 0; ni < 8; ni++) {
        bf16x8 a2 = *(const bf16x8*)(w2c + (wh * 8 + ni) * 1024 + lane * 16);
        acc2[0][ni] = MFMA16(a2, hf0, acc2[0][ni]);
        acc2[1][ni] = MFMA16(a2, hf1, acc2[1][ni]);
      }
      __builtin_amdgcn_s_setprio(0);
    }
    if (notlast) {
      asm volatile("s_waitcnt vmcnt(0) lgkmcnt(0)" ::: "memory");
      __builtin_amdgcn_s_barrier();
    }
  }

#pragma unroll
  for (int ti = 0; ti < 2; ti++) {
    const int tok = toksp[(2 * wt + ti) * 16 + lrow];
    if (tok >= 0) {
#pragma unroll
      for (int ni = 0; ni < 8; ni++) {
        const int n0 = wh * 128 + ni * 16 + lgrp * 4;
        f32x4 bv = *(const f32x4*)(b2s + n0);
        f32x4 v = acc2[ti][ni] + bv;
        *(f32x4*)(out + (size_t)tok * DOUT + n0) = v;
      }
    }
  }
}

extern "C" void kernel_launch(void* const* d_in, const int* in_sizes, int n_in,
                              void* d_out, int out_size, void* d_ws, size_t ws_size,
                              hipStream_t stream) {
  (void)in_sizes; (void)n_in; (void)out_size;
  const float* x   = (const float*)d_in[0];
  const int*   cat = (const int*)d_in[1];
  const float* W1  = (const float*)d_in[2];
  const float* b1  = (const float*)d_in[3];
  const float* W2  = (const float*)d_in[4];
  const float* b2  = (const float*)d_in[5];
  float* out = (float*)d_out;

  char* ws = (char*)d_ws;
  int* counts    = (int*)(ws);
  int* padoff    = (int*)(ws + 128);
  int* blockhist = (int*)(ws + 4096);
  int* base      = (int*)(ws + 65536);
  int* idx       = (int*)(ws + 131072);
  short* w1b     = (short*)(ws + (1 << 20));
  short* w2b     = (short*)(ws + (1 << 20) + 8388608);
  char* hid      = ws + 18874368;                    // hidden @18 MB

  const int nt1 = BB / 128 + CC;                     // 1040 = 8*130
  const size_t need = 18874368ull + (size_t)nt1 * 8 * 32768ull;   // ~291.5 MB
  const bool twopass = (ws_size >= need);

  hist_k<<<NB, 256, 0, stream>>>(cat, blockhist);
  offsets2_k<<<1, 1024, 0, stream>>>(blockhist, counts, padoff, base, twopass ? 128 : FTM);
  scatter2_k<<<NB, 256, 0, stream>>>(cat, base, idx);
  conv_w1_k<<<2048, 256, 0, stream>>>(W1, w1b);
  conv_w2_k<<<2048, 256, 0, stream>>>(W2, w2b);

  if (twopass) {
    p1_k<<<nt1, 512, 0, stream>>>(x, b1, w1b, idx, padoff, counts, hid);
    p2_k<<<nt1, 512, 0, stream>>>(b2, w2b, idx, padoff, counts, hid, out);
  } else {
    const int ntf = BB / FTM + CC;                   // 2064 = 8*258
    mlp_k<<<ntf, 256, 0, stream>>>(x, b1, b2, w1b, w2b, idx, padoff, counts, out);
  }
}

// Round 15
// 245.688 us; speedup vs baseline: 1.5001x; 1.2176x over previous
//
#include <hip/hip_runtime.h>
#include <hip/hip_bf16.h>

#define BB   131072
#define CC   16
#define DIN  256
#define DH   1024
#define DOUT 256
#define TM   64    // tokens per tile
#define NHB  32    // hidden blocks of 32
#define NB   512   // bucketing blocks (BB/NB = 256 tokens each)

typedef __attribute__((ext_vector_type(8))) short bf16x8;
typedef __attribute__((ext_vector_type(4))) short short4v;
typedef __attribute__((ext_vector_type(4))) float f32x4;

__device__ inline unsigned short f2b(float f) {
  union { float f; unsigned u; } v; v.f = f;
  unsigned u = v.u;
  return (unsigned short)((u + 0x7fffu + ((u >> 16) & 1u)) >> 16);  // RNE
}

__device__ inline void gload_lds16(const void* g, void* l) {
  __builtin_amdgcn_global_load_lds(
      (const __attribute__((address_space(1))) void*)g,
      (__attribute__((address_space(3))) void*)l, 16, 0, 0);
}

#define MFMA16(a, b, c) __builtin_amdgcn_mfma_f32_16x16x32_bf16((a), (b), (c), 0, 0, 0)

// ---------------- bucketing (contention-free counting sort) ----------------
__global__ void hist_k(const int* __restrict__ cat, int* __restrict__ blockhist) {
  __shared__ int h[CC];
  const int tid = threadIdx.x;
  if (tid < CC) h[tid] = 0;
  __syncthreads();
  const int i = blockIdx.x * 256 + tid;
  atomicAdd(&h[cat[i]], 1);
  __syncthreads();
  if (tid < CC) blockhist[blockIdx.x * CC + tid] = h[tid];
}

__global__ void offsets2_k(const int* __restrict__ blockhist,
                           int* __restrict__ counts, int* __restrict__ padoff,
                           int* __restrict__ base) {
  __shared__ int part[CC][64];
  __shared__ int pref[CC][64];
  __shared__ int scnt[CC];
  __shared__ int spad[CC + 1];
  const int tid = threadIdx.x;       // 1024 threads
  const int c = tid >> 6;
  const int g = tid & 63;
  int h[8];
  int s = 0;
#pragma unroll
  for (int i = 0; i < 8; i++) {
    h[i] = blockhist[(g * 8 + i) * CC + c];
    s += h[i];
  }
  part[c][g] = s;
  __syncthreads();
  if (g == 0) {
    int r = 0;
    for (int j = 0; j < 64; j++) { pref[c][j] = r; r += part[c][j]; }
    scnt[c] = r;
  }
  __syncthreads();
  if (tid == 0) {
    int acc = 0;
    for (int c2 = 0; c2 < CC; c2++) {
      spad[c2] = acc;
      padoff[c2] = acc;
      counts[c2] = scnt[c2];
      acc += ((scnt[c2] + TM - 1) / TM) * TM;
    }
    spad[CC] = acc;
    padoff[CC] = acc;
  }
  __syncthreads();
  int run = spad[c] + pref[c][g];
#pragma unroll
  for (int i = 0; i < 8; i++) {
    base[(g * 8 + i) * CC + c] = run;
    run += h[i];
  }
}

__global__ void scatter2_k(const int* __restrict__ cat, const int* __restrict__ base,
                           int* __restrict__ idx) {
  __shared__ int cur[CC];
  const int tid = threadIdx.x;
  if (tid < CC) cur[tid] = base[blockIdx.x * CC + tid];
  __syncthreads();
  const int i = blockIdx.x * 256 + tid;
  const int c = cat[i];
  const int pos = atomicAdd(&cur[c], 1);
  idx[pos] = i;
}

// -------- weight conversion: f32 -> bf16 in MFMA A-fragment order --------
// A-frag map (verified r1-r14): 16(row)x32(k) tile, lane = (row&15)+16*((k&31)>>3),
// byte j = (k&7)*2. Tiles stored [tile][lane][16B] = 1024 B.
// W1: per category [hb=32][nt=2][ks=8][lane][16B]  (16 KB per hb of 32 n)
__global__ void conv_w1_k(const float* __restrict__ W1, short* __restrict__ w1b) {
  int t = blockIdx.x * blockDim.x + threadIdx.x;   // 524288
  int n  = t & 1023;
  int j8 = (t >> 10) & 31;   // k-chunk of 8
  int c  = t >> 15;
  const float* src = W1 + (size_t)c * DIN * DH;
  bf16x8 o;
#pragma unroll
  for (int i = 0; i < 8; i++)
    o[i] = (short)f2b(src[(size_t)(j8 * 8 + i) * DH + n]);
  char* dst = (char*)w1b + (size_t)c * 524288
            + (n >> 5) * 16384 + ((n >> 4) & 1) * 8192 + (j8 >> 2) * 1024
            + ((n & 15) + 16 * (j8 & 3)) * 16;
  *(bf16x8*)dst = o;
}

// W2: per category [kb=32][nt=16][lane][16B]  (16 KB per k-block of 32)
__global__ void conv_w2_k(const float* __restrict__ W2, short* __restrict__ w2b) {
  int t = blockIdx.x * blockDim.x + threadIdx.x;   // 524288
  int n  = t & 255;
  int j8 = (t >> 8) & 127;   // k-chunk of 8 (k = hidden)
  int c  = t >> 15;
  const float* src = W2 + (size_t)c * DH * DOUT;
  bf16x8 o;
#pragma unroll
  for (int i = 0; i < 8; i++)
    o[i] = (short)f2b(src[(size_t)(j8 * 8 + i) * DOUT + n]);
  char* dst = (char*)w2b + (size_t)c * 524288
            + (j8 >> 2) * 16384 + (n >> 4) * 1024
            + ((n & 15) + 16 * (j8 & 3)) * 16;
  *(bf16x8*)dst = o;
}

// ---------------- fused routed MLP ----------------
// 256 thr = 4 waves = wt(2: token-tile pair) x wh(2). Tile = 64 tokens.
// w1 DOUBLE-buffered, w2 single-buffered. 42.2 KB LDS -> 3 blocks/CU.
// r15 retiming: BOTH stages issue at A-start:
//   A(i): stage2(i); stage1(i+1); L1; pack hs; vmcnt(4)+lgkm(0)+bar
//         [w2(i) landed ~full-A cover; w1(i+1)'s 4 ops keep flying]
//   B(i): L2; vmcnt(0)+lgkm(0)+bar  [w1(i+1) landed with A+B cover]
// LDS: w1 dbuf 2x16K @0 | w2 16K @32K | hs 4K @48K | toks | b1s | b2s
#define W2OFF  32768
#define HSOFF  49152
#define TKOFF  53248
#define B1OFF  53504
#define B2OFF  57600
#define SMSZ   58624

__launch_bounds__(256, 3)
__global__ void mlp_k(const float* __restrict__ x,
                      const float* __restrict__ b1,
                      const float* __restrict__ b2,
                      const short* __restrict__ w1b,
                      const short* __restrict__ w2b,
                      const int* __restrict__ idx,
                      const int* __restrict__ padoff,
                      const int* __restrict__ counts,
                      float* __restrict__ out) {
  __shared__ __align__(16) char sm[SMSZ];

  const int bhw = blockIdx.x;
  const int wg = (bhw & 7) * 258 + (bhw >> 3);   // XCD-chunked swizzle, 2064 = 8*258
  const int p = wg * TM;
  const int total = padoff[CC];
  if (p >= total) return;
  int c = 0;
  while (padoff[c + 1] <= p) c++;
  const int cnt = counts[c];
  const int start = p - padoff[c];

  const int tid  = threadIdx.x;
  const int lane = tid & 63;
  const int w    = tid >> 6;   // 0..3
  const int wt   = w >> 1;     // 0..1: token-tile pair {2wt, 2wt+1}
  const int wh   = w & 1;      // L1: n-half of 32; L2: out-half of 256
  const int lrow = lane & 15;
  const int lgrp = lane >> 4;

  char*  hsb   = sm + HSOFF;
  int*   toksp = (int*)(sm + TKOFF);
  float* b1s   = (float*)(sm + B1OFF);
  float* b2s   = (float*)(sm + B2OFF);

  // ---- prologue: gather x, f32->bf16, B-frag order [tt=4][ks=8][lane][16B] ----
  // xs occupies sm[0,32K) = w1 dbuf region (freed before staging starts)
  {
    const int r = tid >> 2;      // 0..63 token slot
    const int q = tid & 3;       // 64-float quarter
    const int pos = start + r;
    int tok = (pos < cnt) ? idx[p + r] : -1;
    if (q == 0) toksp[r] = tok;
    char* tb = sm + (r >> 4) * 8192 + (r & 15) * 16;
    if (tok >= 0) {
      const f32x4* src = (const f32x4*)(x + (size_t)tok * DIN) + q * 16;
#pragma unroll
      for (int t = 0; t < 8; t++) {
        f32x4 v0 = src[2 * t];
        f32x4 v1 = src[2 * t + 1];
        bf16x8 o;
        o[0] = (short)f2b(v0[0]); o[1] = (short)f2b(v0[1]);
        o[2] = (short)f2b(v0[2]); o[3] = (short)f2b(v0[3]);
        o[4] = (short)f2b(v1[0]); o[5] = (short)f2b(v1[1]);
        o[6] = (short)f2b(v1[2]); o[7] = (short)f2b(v1[3]);
        *(bf16x8*)(tb + (2 * q + (t >> 2)) * 1024 + (t & 3) * 256) = o;
      }
    } else {
      bf16x8 z = {0, 0, 0, 0, 0, 0, 0, 0};
#pragma unroll
      for (int t = 0; t < 8; t++)
        *(bf16x8*)(tb + (2 * q + (t >> 2)) * 1024 + (t & 3) * 256) = z;
    }
    ((f32x4*)b1s)[tid] = ((const f32x4*)(b1 + (size_t)c * DH))[tid];
    if (tid < 64) ((f32x4*)b2s)[tid] = ((const f32x4*)(b2 + (size_t)c * DOUT))[tid];
  }
  __syncthreads();

  // ---- x fragments to registers: 2 token tiles ----
  bf16x8 xf[2][8];
#pragma unroll
  for (int ti = 0; ti < 2; ti++)
#pragma unroll
    for (int ks = 0; ks < 8; ks++)
      xf[ti][ks] = *(const bf16x8*)(sm + (2 * wt + ti) * 8192 + ks * 1024 + lane * 16);
  __syncthreads();   // xs region free -> w1 dbuf

  const char* w1g = (const char*)w1b + (size_t)c * 524288;
  const char* w2g = (const char*)w2b + (size_t)c * 524288;

  auto stage1 = [&](int i) {   // 16 KB linear into w1 buf (i&1), 4 vm ops/thread
    const char* src = w1g + (size_t)i * 16384;
    char* dst = sm + (i & 1) * 16384;
#pragma unroll
    for (int j = 0; j < 4; j++) {
      int chunk = (w * 4 + j) * 1024;
      gload_lds16(src + chunk + lane * 16, dst + chunk);
    }
  };
  auto stage2 = [&](int i) {   // 16 KB linear, 4 vm ops/thread
    const char* src = w2g + (size_t)i * 16384;
#pragma unroll
    for (int j = 0; j < 4; j++) {
      int chunk = (w * 4 + j) * 1024;
      gload_lds16(src + chunk + lane * 16, sm + W2OFF + chunk);
    }
  };

  stage1(0);
  asm volatile("s_waitcnt vmcnt(0)" ::: "memory");
  __syncthreads();   // w1[0] ready

  f32x4 acc2[2][8];   // [token tile][out tile]
#pragma unroll
  for (int ti = 0; ti < 2; ti++)
#pragma unroll
    for (int ni = 0; ni < 8; ni++)
      acc2[ti][ni] = (f32x4){0.f, 0.f, 0.f, 0.f};

  // hs write position (D-frag -> B-frag order), constant per thread:
  const int hswr = (lrow + 16 * (wh * 2 + (lgrp >> 1))) * 16 + (lgrp & 1) * 8;
  const char* w2c = sm + W2OFF;

  for (int hb = 0; hb < NHB; hb++) {
    const bool notlast = (hb < NHB - 1);
    const char* w1c = sm + (hb & 1) * 16384 + wh * 8192;

    // ===== region A: issue stage2(hb) THEN stage1(hb+1) (into w1 buf^1, safe
    //       with dbuf); L1 (8 reads -> 16 MFMA); relu -> hs =====
    stage2(hb);                    // safe: B(hb-1) end-barrier drained w2 reads
    if (notlast) stage1(hb + 1);   // safe: writes the OTHER w1 buffer

    f32x4 p0 = (f32x4){0.f, 0.f, 0.f, 0.f};
    f32x4 p1 = (f32x4){0.f, 0.f, 0.f, 0.f};
    __builtin_amdgcn_s_setprio(1);
#pragma unroll
    for (int ks = 0; ks < 8; ks++) {
      bf16x8 a = *(const bf16x8*)(w1c + ks * 1024 + lane * 16);
      p0 = MFMA16(a, xf[0][ks], p0);
      p1 = MFMA16(a, xf[1][ks], p1);
    }
    __builtin_amdgcn_s_setprio(0);

    {
      f32x4 bv = *(const f32x4*)(b1s + hb * 32 + wh * 16 + lgrp * 4);
      short4v h0, h1;
#pragma unroll
      for (int jj = 0; jj < 4; jj++) {
        h0[jj] = (short)f2b(fmaxf(p0[jj] + bv[jj], 0.0f));
        h1[jj] = (short)f2b(fmaxf(p1[jj] + bv[jj], 0.0f));
      }
      *(short4v*)(hsb + (2 * wt) * 1024 + hswr)     = h0;
      *(short4v*)(hsb + (2 * wt + 1) * 1024 + hswr) = h1;
    }
    // counted drain: stage2's 4 ops done (full-A cover); stage1's 4 keep flying
    if (notlast)
      asm volatile("s_waitcnt vmcnt(4) lgkmcnt(0)" ::: "memory");
    else
      asm volatile("s_waitcnt vmcnt(0) lgkmcnt(0)" ::: "memory");
    __builtin_amdgcn_s_barrier();

    // ===== region B: L2 (10 reads -> 16 MFMA) =====
    {
      bf16x8 hf0 = *(const bf16x8*)(hsb + (2 * wt) * 1024 + lane * 16);
      bf16x8 hf1 = *(const bf16x8*)(hsb + (2 * wt + 1) * 1024 + lane * 16);
      __builtin_amdgcn_s_setprio(1);
#pragma unroll
      for (int ni = 0; ni < 8; ni++) {
        bf16x8 a2 = *(const bf16x8*)(w2c + (wh * 8 + ni) * 1024 + lane * 16);
        acc2[0][ni] = MFMA16(a2, hf0, acc2[0][ni]);
        acc2[1][ni] = MFMA16(a2, hf1, acc2[1][ni]);
      }
      __builtin_amdgcn_s_setprio(0);
    }
    // w1(hb+1) landed (A+B cover); hs reads drained before next A rewrites
    if (notlast) {
      asm volatile("s_waitcnt vmcnt(0) lgkmcnt(0)" ::: "memory");
      __builtin_amdgcn_s_barrier();
    }
  }

  // ---- epilogue: + b2, vectorized scatter ----
#pragma unroll
  for (int ti = 0; ti < 2; ti++) {
    const int tok = toksp[(2 * wt + ti) * 16 + lrow];
    if (tok >= 0) {
#pragma unroll
      for (int ni = 0; ni < 8; ni++) {
        const int n0 = wh * 128 + ni * 16 + lgrp * 4;
        f32x4 bv = *(const f32x4*)(b2s + n0);
        f32x4 v = acc2[ti][ni] + bv;
        *(f32x4*)(out + (size_t)tok * DOUT + n0) = v;
      }
    }
  }
}

extern "C" void kernel_launch(void* const* d_in, const int* in_sizes, int n_in,
                              void* d_out, int out_size, void* d_ws, size_t ws_size,
                              hipStream_t stream) {
  (void)in_sizes; (void)n_in; (void)out_size; (void)ws_size;
  const float* x   = (const float*)d_in[0];
  const int*   cat = (const int*)d_in[1];
  const float* W1  = (const float*)d_in[2];
  const float* b1  = (const float*)d_in[3];
  const float* W2  = (const float*)d_in[4];
  const float* b2  = (const float*)d_in[5];
  float* out = (float*)d_out;

  char* ws = (char*)d_ws;
  int* counts    = (int*)(ws);
  int* padoff    = (int*)(ws + 128);
  int* blockhist = (int*)(ws + 4096);
  int* base      = (int*)(ws + 65536);
  int* idx       = (int*)(ws + 131072);
  short* w1b     = (short*)(ws + (1 << 20));
  short* w2b     = (short*)(ws + (1 << 20) + 8388608);

  hist_k<<<NB, 256, 0, stream>>>(cat, blockhist);
  offsets2_k<<<1, 1024, 0, stream>>>(blockhist, counts, padoff, base);
  scatter2_k<<<NB, 256, 0, stream>>>(cat, base, idx);
  conv_w1_k<<<2048, 256, 0, stream>>>(W1, w1b);
  conv_w2_k<<<2048, 256, 0, stream>>>(W2, w2b);

  const int ntiles = BB / TM + CC;   // 2064 = 8 * 258 (swizzle assumes this)
  mlp_k<<<ntiles, 256, 0, stream>>>(x, b1, b2, w1b, w2b, idx, padoff, counts, out);
}

// Round 16
// 223.535 us; speedup vs baseline: 1.6487x; 1.0991x over previous
//
#include <hip/hip_runtime.h>
#include <hip/hip_bf16.h>

#define BB   131072
#define CC   16
#define DIN  256
#define DH   1024
#define DOUT 256
#define TM   64    // tokens per tile
#define NHB  32    // hidden blocks of 32
#define NB   512   // bucketing blocks (BB/NB = 256 tokens each)

typedef __attribute__((ext_vector_type(8))) short bf16x8;
typedef __attribute__((ext_vector_type(4))) short short4v;
typedef __attribute__((ext_vector_type(4))) float f32x4;

__device__ inline unsigned short f2b(float f) {
  union { float f; unsigned u; } v; v.f = f;
  unsigned u = v.u;
  return (unsigned short)((u + 0x7fffu + ((u >> 16) & 1u)) >> 16);  // RNE
}

__device__ inline void gload_lds16(const void* g, void* l) {
  __builtin_amdgcn_global_load_lds(
      (const __attribute__((address_space(1))) void*)g,
      (__attribute__((address_space(3))) void*)l, 16, 0, 0);
}

#define MFMA16(a, b, c) __builtin_amdgcn_mfma_f32_16x16x32_bf16((a), (b), (c), 0, 0, 0)

// ---------------- bucketing (contention-free counting sort) ----------------
__global__ void hist_k(const int* __restrict__ cat, int* __restrict__ blockhist) {
  __shared__ int h[CC];
  const int tid = threadIdx.x;
  if (tid < CC) h[tid] = 0;
  __syncthreads();
  const int i = blockIdx.x * 256 + tid;
  atomicAdd(&h[cat[i]], 1);
  __syncthreads();
  if (tid < CC) blockhist[blockIdx.x * CC + tid] = h[tid];
}

__global__ void offsets2_k(const int* __restrict__ blockhist,
                           int* __restrict__ counts, int* __restrict__ padoff,
                           int* __restrict__ base) {
  __shared__ int part[CC][64];
  __shared__ int pref[CC][64];
  __shared__ int scnt[CC];
  __shared__ int spad[CC + 1];
  const int tid = threadIdx.x;       // 1024 threads
  const int c = tid >> 6;
  const int g = tid & 63;
  int h[8];
  int s = 0;
#pragma unroll
  for (int i = 0; i < 8; i++) {
    h[i] = blockhist[(g * 8 + i) * CC + c];
    s += h[i];
  }
  part[c][g] = s;
  __syncthreads();
  if (g == 0) {
    int r = 0;
    for (int j = 0; j < 64; j++) { pref[c][j] = r; r += part[c][j]; }
    scnt[c] = r;
  }
  __syncthreads();
  if (tid == 0) {
    int acc = 0;
    for (int c2 = 0; c2 < CC; c2++) {
      spad[c2] = acc;
      padoff[c2] = acc;
      counts[c2] = scnt[c2];
      acc += ((scnt[c2] + TM - 1) / TM) * TM;
    }
    spad[CC] = acc;
    padoff[CC] = acc;
  }
  __syncthreads();
  int run = spad[c] + pref[c][g];
#pragma unroll
  for (int i = 0; i < 8; i++) {
    base[(g * 8 + i) * CC + c] = run;
    run += h[i];
  }
}

__global__ void scatter2_k(const int* __restrict__ cat, const int* __restrict__ base,
                           int* __restrict__ idx) {
  __shared__ int cur[CC];
  const int tid = threadIdx.x;
  if (tid < CC) cur[tid] = base[blockIdx.x * CC + tid];
  __syncthreads();
  const int i = blockIdx.x * 256 + tid;
  const int c = cat[i];
  const int pos = atomicAdd(&cur[c], 1);
  idx[pos] = i;
}

// -------- weight conversion: f32 -> bf16 in MFMA A-fragment order --------
// A-frag map (verified r1-r15): 16(row)x32(k) tile, lane = (row&15)+16*((k&31)>>3),
// byte j = (k&7)*2. Tiles stored [tile][lane][16B] = 1024 B.
// W1: per category [hb=32][nt=2][ks=8][lane][16B]  (16 KB per hb of 32 n)
__global__ void conv_w1_k(const float* __restrict__ W1, short* __restrict__ w1b) {
  int t = blockIdx.x * blockDim.x + threadIdx.x;   // 524288
  int n  = t & 1023;
  int j8 = (t >> 10) & 31;   // k-chunk of 8
  int c  = t >> 15;
  const float* src = W1 + (size_t)c * DIN * DH;
  bf16x8 o;
#pragma unroll
  for (int i = 0; i < 8; i++)
    o[i] = (short)f2b(src[(size_t)(j8 * 8 + i) * DH + n]);
  char* dst = (char*)w1b + (size_t)c * 524288
            + (n >> 5) * 16384 + ((n >> 4) & 1) * 8192 + (j8 >> 2) * 1024
            + ((n & 15) + 16 * (j8 & 3)) * 16;
  *(bf16x8*)dst = o;
}

// W2: per category [kb=32][nt=16][lane][16B]  (16 KB per k-block of 32)
__global__ void conv_w2_k(const float* __restrict__ W2, short* __restrict__ w2b) {
  int t = blockIdx.x * blockDim.x + threadIdx.x;   // 524288
  int n  = t & 255;
  int j8 = (t >> 8) & 127;   // k-chunk of 8 (k = hidden)
  int c  = t >> 15;
  const float* src = W2 + (size_t)c * DH * DOUT;
  bf16x8 o;
#pragma unroll
  for (int i = 0; i < 8; i++)
    o[i] = (short)f2b(src[(size_t)(j8 * 8 + i) * DOUT + n]);
  char* dst = (char*)w2b + (size_t)c * 524288
            + (j8 >> 2) * 16384 + (n >> 4) * 1024
            + ((n & 15) + 16 * (j8 & 3)) * 16;
  *(bf16x8*)dst = o;
}

// ---------------- fused routed MLP ----------------
// 256 thr = 4 waves = wt(2: token-tile pair) x wh(2). Tile = 64 tokens.
// w1 DOUBLE-buffered, w2 single. Biases NOT in LDS (b1: per-hb global broadcast
// load; b2: epilogue global load) -> 53504 B LDS -> 3 blocks/CU (the r12 TLP)
// WITH the r15 retiming:
//   A(i): b1v load; stage2(i); stage1(i+1); L1; [vmcnt(8) auto] pack hs;
//         vmcnt(4)+lgkm(0)+bar   [w2(i) landed full-A cover; stage1 flies on]
//   B(i): L2; vmcnt(0)+lgkm(0)+bar  [w1(i+1) landed with A+B cover]
// LDS: w1 dbuf 2x16K @0 | w2 16K @32K | hs 4K @48K | toks @52K  (53504 B)
#define W2OFF  32768
#define HSOFF  49152
#define TKOFF  53248
#define SMSZ   53504

__launch_bounds__(256, 3)
__global__ void mlp_k(const float* __restrict__ x,
                      const float* __restrict__ b1,
                      const float* __restrict__ b2,
                      const short* __restrict__ w1b,
                      const short* __restrict__ w2b,
                      const int* __restrict__ idx,
                      const int* __restrict__ padoff,
                      const int* __restrict__ counts,
                      float* __restrict__ out) {
  __shared__ __align__(16) char sm[SMSZ];

  const int bhw = blockIdx.x;
  const int wg = (bhw & 7) * 258 + (bhw >> 3);   // XCD-chunked swizzle, 2064 = 8*258
  const int p = wg * TM;
  const int total = padoff[CC];
  if (p >= total) return;
  int c = 0;
  while (padoff[c + 1] <= p) c++;
  const int cnt = counts[c];
  const int start = p - padoff[c];

  const int tid  = threadIdx.x;
  const int lane = tid & 63;
  const int w    = tid >> 6;   // 0..3
  const int wt   = w >> 1;     // 0..1: token-tile pair {2wt, 2wt+1}
  const int wh   = w & 1;      // L1: n-half of 32; L2: out-half of 256
  const int lrow = lane & 15;
  const int lgrp = lane >> 4;

  char*  hsb   = sm + HSOFF;
  int*   toksp = (int*)(sm + TKOFF);

  // ---- prologue: gather x, f32->bf16, B-frag order [tt=4][ks=8][lane][16B] ----
  // xs occupies sm[0,32K) = w1 dbuf region (freed before staging starts)
  {
    const int r = tid >> 2;      // 0..63 token slot
    const int q = tid & 3;       // 64-float quarter
    const int pos = start + r;
    int tok = (pos < cnt) ? idx[p + r] : -1;
    if (q == 0) toksp[r] = tok;
    char* tb = sm + (r >> 4) * 8192 + (r & 15) * 16;
    if (tok >= 0) {
      const f32x4* src = (const f32x4*)(x + (size_t)tok * DIN) + q * 16;
#pragma unroll
      for (int t = 0; t < 8; t++) {
        f32x4 v0 = src[2 * t];
        f32x4 v1 = src[2 * t + 1];
        bf16x8 o;
        o[0] = (short)f2b(v0[0]); o[1] = (short)f2b(v0[1]);
        o[2] = (short)f2b(v0[2]); o[3] = (short)f2b(v0[3]);
        o[4] = (short)f2b(v1[0]); o[5] = (short)f2b(v1[1]);
        o[6] = (short)f2b(v1[2]); o[7] = (short)f2b(v1[3]);
        *(bf16x8*)(tb + (2 * q + (t >> 2)) * 1024 + (t & 3) * 256) = o;
      }
    } else {
      bf16x8 z = {0, 0, 0, 0, 0, 0, 0, 0};
#pragma unroll
      for (int t = 0; t < 8; t++)
        *(bf16x8*)(tb + (2 * q + (t >> 2)) * 1024 + (t & 3) * 256) = z;
    }
  }
  __syncthreads();

  // ---- x fragments to registers: 2 token tiles ----
  bf16x8 xf[2][8];
#pragma unroll
  for (int ti = 0; ti < 2; ti++)
#pragma unroll
    for (int ks = 0; ks < 8; ks++)
      xf[ti][ks] = *(const bf16x8*)(sm + (2 * wt + ti) * 8192 + ks * 1024 + lane * 16);
  __syncthreads();   // xs region free -> w1 dbuf

  const char* w1g = (const char*)w1b + (size_t)c * 524288;
  const char* w2g = (const char*)w2b + (size_t)c * 524288;
  const float* b1g = b1 + (size_t)c * DH + wh * 16 + lgrp * 4;

  auto stage1 = [&](int i) {   // 16 KB linear into w1 buf (i&1), 4 vm ops/thread
    const char* src = w1g + (size_t)i * 16384;
    char* dst = sm + (i & 1) * 16384;
#pragma unroll
    for (int j = 0; j < 4; j++) {
      int chunk = (w * 4 + j) * 1024;
      gload_lds16(src + chunk + lane * 16, dst + chunk);
    }
  };
  auto stage2 = [&](int i) {   // 16 KB linear, 4 vm ops/thread
    const char* src = w2g + (size_t)i * 16384;
#pragma unroll
    for (int j = 0; j < 4; j++) {
      int chunk = (w * 4 + j) * 1024;
      gload_lds16(src + chunk + lane * 16, sm + W2OFF + chunk);
    }
  };

  stage1(0);
  asm volatile("s_waitcnt vmcnt(0)" ::: "memory");
  __syncthreads();   // w1[0] ready

  f32x4 acc2[2][8];   // [token tile][out tile]
#pragma unroll
  for (int ti = 0; ti < 2; ti++)
#pragma unroll
    for (int ni = 0; ni < 8; ni++)
      acc2[ti][ni] = (f32x4){0.f, 0.f, 0.f, 0.f};

  // hs write position (D-frag -> B-frag order), constant per thread:
  const int hswr = (lrow + 16 * (wh * 2 + (lgrp >> 1))) * 16 + (lgrp & 1) * 8;
  const char* w2c = sm + W2OFF;

  for (int hb = 0; hb < NHB; hb++) {
    const bool notlast = (hb < NHB - 1);
    const char* w1c = sm + (hb & 1) * 16384 + wh * 8192;

    // ===== region A =====
    // b1 broadcast load FIRST (oldest) so the auto-wait at pack is counted,
    // not a drain; sched_barrier pins it before the stages.
    f32x4 bv = *(const f32x4*)(b1g + hb * 32);
    __builtin_amdgcn_sched_barrier(0);
    stage2(hb);                    // safe: B(hb-1) end-barrier drained w2 reads
    if (notlast) stage1(hb + 1);   // safe: writes the OTHER w1 buffer

    f32x4 p0 = (f32x4){0.f, 0.f, 0.f, 0.f};
    f32x4 p1 = (f32x4){0.f, 0.f, 0.f, 0.f};
    __builtin_amdgcn_s_setprio(1);
#pragma unroll
    for (int ks = 0; ks < 8; ks++) {
      bf16x8 a = *(const bf16x8*)(w1c + ks * 1024 + lane * 16);
      p0 = MFMA16(a, xf[0][ks], p0);
      p1 = MFMA16(a, xf[1][ks], p1);
    }
    __builtin_amdgcn_s_setprio(0);

    {
      short4v h0, h1;
#pragma unroll
      for (int jj = 0; jj < 4; jj++) {
        h0[jj] = (short)f2b(fmaxf(p0[jj] + bv[jj], 0.0f));
        h1[jj] = (short)f2b(fmaxf(p1[jj] + bv[jj], 0.0f));
      }
      *(short4v*)(hsb + (2 * wt) * 1024 + hswr)     = h0;
      *(short4v*)(hsb + (2 * wt + 1) * 1024 + hswr) = h1;
    }
    // counted drain: bv + stage2's 4 done (full-A cover); stage1's 4 keep flying
    if (notlast)
      asm volatile("s_waitcnt vmcnt(4) lgkmcnt(0)" ::: "memory");
    else
      asm volatile("s_waitcnt vmcnt(0) lgkmcnt(0)" ::: "memory");
    __builtin_amdgcn_s_barrier();

    // ===== region B: L2 (10 reads -> 16 MFMA) =====
    {
      bf16x8 hf0 = *(const bf16x8*)(hsb + (2 * wt) * 1024 + lane * 16);
      bf16x8 hf1 = *(const bf16x8*)(hsb + (2 * wt + 1) * 1024 + lane * 16);
      __builtin_amdgcn_s_setprio(1);
#pragma unroll
      for (int ni = 0; ni < 8; ni++) {
        bf16x8 a2 = *(const bf16x8*)(w2c + (wh * 8 + ni) * 1024 + lane * 16);
        acc2[0][ni] = MFMA16(a2, hf0, acc2[0][ni]);
        acc2[1][ni] = MFMA16(a2, hf1, acc2[1][ni]);
      }
      __builtin_amdgcn_s_setprio(0);
    }
    // w1(hb+1) landed (A+B cover); hs reads drained before next A rewrites
    if (notlast) {
      asm volatile("s_waitcnt vmcnt(0) lgkmcnt(0)" ::: "memory");
      __builtin_amdgcn_s_barrier();
    }
  }

  // ---- epilogue: + b2 (global, one-time), vectorized scatter ----
#pragma unroll
  for (int ti = 0; ti < 2; ti++) {
    const int tok = toksp[(2 * wt + ti) * 16 + lrow];
    if (tok >= 0) {
#pragma unroll
      for (int ni = 0; ni < 8; ni++) {
        const int n0 = wh * 128 + ni * 16 + lgrp * 4;
        f32x4 bv2 = *(const f32x4*)(b2 + (size_t)c * DOUT + n0);
        f32x4 v = acc2[ti][ni] + bv2;
        *(f32x4*)(out + (size_t)tok * DOUT + n0) = v;
      }
    }
  }
}

extern "C" void kernel_launch(void* const* d_in, const int* in_sizes, int n_in,
                              void* d_out, int out_size, void* d_ws, size_t ws_size,
                              hipStream_t stream) {
  (void)in_sizes; (void)n_in; (void)out_size; (void)ws_size;
  const float* x   = (const float*)d_in[0];
  const int*   cat = (const int*)d_in[1];
  const float* W1  = (const float*)d_in[2];
  const float* b1  = (const float*)d_in[3];
  const float* W2  = (const float*)d_in[4];
  const float* b2  = (const float*)d_in[5];
  float* out = (float*)d_out;

  char* ws = (char*)d_ws;
  int* counts    = (int*)(ws);
  int* padoff    = (int*)(ws + 128);
  int* blockhist = (int*)(ws + 4096);
  int* base      = (int*)(ws + 65536);
  int* idx       = (int*)(ws + 131072);
  short* w1b     = (short*)(ws + (1 << 20));
  short* w2b     = (short*)(ws + (1 << 20) + 8388608);

  hist_k<<<NB, 256, 0, stream>>>(cat, blockhist);
  offsets2_k<<<1, 1024, 0, stream>>>(blockhist, counts, padoff, base);
  scatter2_k<<<NB, 256, 0, stream>>>(cat, base, idx);
  conv_w1_k<<<2048, 256, 0, stream>>>(W1, w1b);
  conv_w2_k<<<2048, 256, 0, stream>>>(W2, w2b);

  const int ntiles = BB / TM + CC;   // 2064 = 8 * 258 (swizzle assumes this)
  mlp_k<<<ntiles, 256, 0, stream>>>(x, b1, b2, w1b, w2b, idx, padoff, counts, out);
}

// Round 17
// 217.569 us; speedup vs baseline: 1.6939x; 1.0274x over previous
//
#include <hip/hip_runtime.h>
#include <hip/hip_bf16.h>

#define BB   131072
#define CC   16
#define DIN  256
#define DH   1024
#define DOUT 256
#define TM   64    // tokens per tile
#define NHB  32    // hidden blocks of 32
#define NB   512   // bucketing blocks (BB/NB = 256 tokens each)

typedef __attribute__((ext_vector_type(8))) short bf16x8;
typedef __attribute__((ext_vector_type(4))) short short4v;
typedef __attribute__((ext_vector_type(4))) float f32x4;

__device__ inline unsigned short f2b(float f) {
  union { float f; unsigned u; } v; v.f = f;
  unsigned u = v.u;
  return (unsigned short)((u + 0x7fffu + ((u >> 16) & 1u)) >> 16);  // RNE
}

__device__ inline void gload_lds16(const void* g, void* l) {
  __builtin_amdgcn_global_load_lds(
      (const __attribute__((address_space(1))) void*)g,
      (__attribute__((address_space(3))) void*)l, 16, 0, 0);
}

#define MFMA16(a, b, c) __builtin_amdgcn_mfma_f32_16x16x32_bf16((a), (b), (c), 0, 0, 0)

// ---------------- bucketing (contention-free counting sort) ----------------
__global__ void hist_k(const int* __restrict__ cat, int* __restrict__ blockhist) {
  __shared__ int h[CC];
  const int tid = threadIdx.x;
  if (tid < CC) h[tid] = 0;
  __syncthreads();
  const int i = blockIdx.x * 256 + tid;
  atomicAdd(&h[cat[i]], 1);
  __syncthreads();
  if (tid < CC) blockhist[blockIdx.x * CC + tid] = h[tid];
}

__global__ void offsets2_k(const int* __restrict__ blockhist,
                           int* __restrict__ counts, int* __restrict__ padoff,
                           int* __restrict__ base) {
  __shared__ int part[CC][64];
  __shared__ int pref[CC][64];
  __shared__ int scnt[CC];
  __shared__ int spad[CC + 1];
  const int tid = threadIdx.x;       // 1024 threads
  const int c = tid >> 6;
  const int g = tid & 63;
  int h[8];
  int s = 0;
#pragma unroll
  for (int i = 0; i < 8; i++) {
    h[i] = blockhist[(g * 8 + i) * CC + c];
    s += h[i];
  }
  part[c][g] = s;
  __syncthreads();
  if (g == 0) {
    int r = 0;
    for (int j = 0; j < 64; j++) { pref[c][j] = r; r += part[c][j]; }
    scnt[c] = r;
  }
  __syncthreads();
  if (tid == 0) {
    int acc = 0;
    for (int c2 = 0; c2 < CC; c2++) {
      spad[c2] = acc;
      padoff[c2] = acc;
      counts[c2] = scnt[c2];
      acc += ((scnt[c2] + TM - 1) / TM) * TM;
    }
    spad[CC] = acc;
    padoff[CC] = acc;
  }
  __syncthreads();
  int run = spad[c] + pref[c][g];
#pragma unroll
  for (int i = 0; i < 8; i++) {
    base[(g * 8 + i) * CC + c] = run;
    run += h[i];
  }
}

__global__ void scatter2_k(const int* __restrict__ cat, const int* __restrict__ base,
                           int* __restrict__ idx) {
  __shared__ int cur[CC];
  const int tid = threadIdx.x;
  if (tid < CC) cur[tid] = base[blockIdx.x * CC + tid];
  __syncthreads();
  const int i = blockIdx.x * 256 + tid;
  const int c = cat[i];
  const int pos = atomicAdd(&cur[c], 1);
  idx[pos] = i;
}

// -------- weight conversion: f32 -> bf16 in MFMA A-fragment order --------
// A-frag map (verified r1-r16): 16(row)x32(k) tile, lane = (row&15)+16*((k&31)>>3),
// byte j = (k&7)*2. Tiles stored [tile][lane][16B] = 1024 B.
// W1: per category [hb=32][nt=2][ks=8][lane][16B]  (16 KB per hb of 32 n)
__global__ void conv_w1_k(const float* __restrict__ W1, short* __restrict__ w1b) {
  int t = blockIdx.x * blockDim.x + threadIdx.x;   // 524288
  int n  = t & 1023;
  int j8 = (t >> 10) & 31;   // k-chunk of 8
  int c  = t >> 15;
  const float* src = W1 + (size_t)c * DIN * DH;
  bf16x8 o;
#pragma unroll
  for (int i = 0; i < 8; i++)
    o[i] = (short)f2b(src[(size_t)(j8 * 8 + i) * DH + n]);
  char* dst = (char*)w1b + (size_t)c * 524288
            + (n >> 5) * 16384 + ((n >> 4) & 1) * 8192 + (j8 >> 2) * 1024
            + ((n & 15) + 16 * (j8 & 3)) * 16;
  *(bf16x8*)dst = o;
}

// W2: per category [kb=32][nt=16][lane][16B]  (16 KB per k-block of 32)
__global__ void conv_w2_k(const float* __restrict__ W2, short* __restrict__ w2b) {
  int t = blockIdx.x * blockDim.x + threadIdx.x;   // 524288
  int n  = t & 255;
  int j8 = (t >> 8) & 127;   // k-chunk of 8 (k = hidden)
  int c  = t >> 15;
  const float* src = W2 + (size_t)c * DH * DOUT;
  bf16x8 o;
#pragma unroll
  for (int i = 0; i < 8; i++)
    o[i] = (short)f2b(src[(size_t)(j8 * 8 + i) * DOUT + n]);
  char* dst = (char*)w2b + (size_t)c * 524288
            + (j8 >> 2) * 16384 + (n >> 4) * 1024
            + ((n & 15) + 16 * (j8 & 3)) * 16;
  *(bf16x8*)dst = o;
}

// ---------------- fused routed MLP (r12 + 4-way L1 ILP chains) ----------------
// 256 thr = 4 waves = wt(2: token-tile pair) x wh(2). Tile = 64 tokens.
// SINGLE-buffered w1/w2 (42.2 KB LDS -> 3 blocks/CU = 12 waves/CU TLP).
//   A(i): issue stage2(i); L1 (8 reads -> 16 MFMA, 4 indep chains); pack hs;
//         vmcnt(0)+lgkm(0)+bar
//   B(i): issue stage1(i+1); L2 (10 reads -> 16 MFMA, 16 indep accs);
//         vmcnt(0)+lgkm(0)+bar
// LDS: w1 16K @0 | w2 16K @16K | hs 4K @32K | toks | b1s | b2s  (42240 B)
#define W2OFF  16384
#define HSOFF  32768
#define TKOFF  36864
#define B1OFF  37120
#define B2OFF  41216
#define SMSZ   42240

__launch_bounds__(256, 3)
__global__ void mlp_k(const float* __restrict__ x,
                      const float* __restrict__ b1,
                      const float* __restrict__ b2,
                      const short* __restrict__ w1b,
                      const short* __restrict__ w2b,
                      const int* __restrict__ idx,
                      const int* __restrict__ padoff,
                      const int* __restrict__ counts,
                      float* __restrict__ out) {
  __shared__ __align__(16) char sm[SMSZ];

  const int bhw = blockIdx.x;
  const int wg = (bhw & 7) * 258 + (bhw >> 3);   // XCD-chunked swizzle, 2064 = 8*258
  const int p = wg * TM;
  const int total = padoff[CC];
  if (p >= total) return;
  int c = 0;
  while (padoff[c + 1] <= p) c++;
  const int cnt = counts[c];
  const int start = p - padoff[c];

  const int tid  = threadIdx.x;
  const int lane = tid & 63;
  const int w    = tid >> 6;   // 0..3
  const int wt   = w >> 1;     // 0..1: token-tile pair {2wt, 2wt+1}
  const int wh   = w & 1;      // L1: n-half of 32; L2: out-half of 256
  const int lrow = lane & 15;
  const int lgrp = lane >> 4;

  char*  hsb   = sm + HSOFF;
  int*   toksp = (int*)(sm + TKOFF);
  float* b1s   = (float*)(sm + B1OFF);
  float* b2s   = (float*)(sm + B2OFF);

  // ---- prologue: gather x, f32->bf16, B-frag order [tt=4][ks=8][lane][16B] ----
  // xs occupies sm[0,32K) = w1s+w2s region (freed before staging starts)
  {
    const int r = tid >> 2;      // 0..63 token slot
    const int q = tid & 3;       // 64-float quarter
    const int pos = start + r;
    int tok = (pos < cnt) ? idx[p + r] : -1;
    if (q == 0) toksp[r] = tok;
    char* tb = sm + (r >> 4) * 8192 + (r & 15) * 16;
    if (tok >= 0) {
      const f32x4* src = (const f32x4*)(x + (size_t)tok * DIN) + q * 16;
#pragma unroll
      for (int t = 0; t < 8; t++) {
        f32x4 v0 = src[2 * t];
        f32x4 v1 = src[2 * t + 1];
        bf16x8 o;
        o[0] = (short)f2b(v0[0]); o[1] = (short)f2b(v0[1]);
        o[2] = (short)f2b(v0[2]); o[3] = (short)f2b(v0[3]);
        o[4] = (short)f2b(v1[0]); o[5] = (short)f2b(v1[1]);
        o[6] = (short)f2b(v1[2]); o[7] = (short)f2b(v1[3]);
        *(bf16x8*)(tb + (2 * q + (t >> 2)) * 1024 + (t & 3) * 256) = o;
      }
    } else {
      bf16x8 z = {0, 0, 0, 0, 0, 0, 0, 0};
#pragma unroll
      for (int t = 0; t < 8; t++)
        *(bf16x8*)(tb + (2 * q + (t >> 2)) * 1024 + (t & 3) * 256) = z;
    }
    ((f32x4*)b1s)[tid] = ((const f32x4*)(b1 + (size_t)c * DH))[tid];
    if (tid < 64) ((f32x4*)b2s)[tid] = ((const f32x4*)(b2 + (size_t)c * DOUT))[tid];
  }
  __syncthreads();

  // ---- x fragments to registers: 2 token tiles ----
  bf16x8 xf[2][8];
#pragma unroll
  for (int ti = 0; ti < 2; ti++)
#pragma unroll
    for (int ks = 0; ks < 8; ks++)
      xf[ti][ks] = *(const bf16x8*)(sm + (2 * wt + ti) * 8192 + ks * 1024 + lane * 16);
  __syncthreads();   // xs region free -> weight buffers

  const char* w1g = (const char*)w1b + (size_t)c * 524288;
  const char* w2g = (const char*)w2b + (size_t)c * 524288;

  auto stage1 = [&](int i) {   // 16 KB linear, 4 vm ops/thread
    const char* src = w1g + (size_t)i * 16384;
#pragma unroll
    for (int j = 0; j < 4; j++) {
      int chunk = (w * 4 + j) * 1024;
      gload_lds16(src + chunk + lane * 16, sm + chunk);
    }
  };
  auto stage2 = [&](int i) {   // 16 KB linear, 4 vm ops/thread
    const char* src = w2g + (size_t)i * 16384;
#pragma unroll
    for (int j = 0; j < 4; j++) {
      int chunk = (w * 4 + j) * 1024;
      gload_lds16(src + chunk + lane * 16, sm + W2OFF + chunk);
    }
  };

  stage1(0);
  asm volatile("s_waitcnt vmcnt(0)" ::: "memory");
  __syncthreads();   // w1[0] ready

  f32x4 acc2[2][8];   // [token tile][out tile]
#pragma unroll
  for (int ti = 0; ti < 2; ti++)
#pragma unroll
    for (int ni = 0; ni < 8; ni++)
      acc2[ti][ni] = (f32x4){0.f, 0.f, 0.f, 0.f};

  // hs write position (D-frag -> B-frag order), constant per thread:
  const int hswr = (lrow + 16 * (wh * 2 + (lgrp >> 1))) * 16 + (lgrp & 1) * 8;
  const char* w1c = sm + wh * 8192;
  const char* w2c = sm + W2OFF;

  for (int hb = 0; hb < NHB; hb++) {
    const bool notlast = (hb < NHB - 1);

    // ===== region A: issue stage2(hb); L1 (8 reads -> 16 MFMA, 4 chains) =====
    stage2(hb);   // safe: B(hb-1) end-barrier drained all w2 reads

    f32x4 p0a = (f32x4){0.f, 0.f, 0.f, 0.f};
    f32x4 p0b = (f32x4){0.f, 0.f, 0.f, 0.f};
    f32x4 p1a = (f32x4){0.f, 0.f, 0.f, 0.f};
    f32x4 p1b = (f32x4){0.f, 0.f, 0.f, 0.f};
    __builtin_amdgcn_s_setprio(1);
#pragma unroll
    for (int ks = 0; ks < 8; ks += 2) {
      bf16x8 a0 = *(const bf16x8*)(w1c + ks * 1024 + lane * 16);
      bf16x8 a1 = *(const bf16x8*)(w1c + (ks + 1) * 1024 + lane * 16);
      p0a = MFMA16(a0, xf[0][ks], p0a);
      p1a = MFMA16(a0, xf[1][ks], p1a);
      p0b = MFMA16(a1, xf[0][ks + 1], p0b);
      p1b = MFMA16(a1, xf[1][ks + 1], p1b);
    }
    __builtin_amdgcn_s_setprio(0);

    {
      f32x4 bv = *(const f32x4*)(b1s + hb * 32 + wh * 16 + lgrp * 4);
      f32x4 s0 = p0a + p0b + bv;
      f32x4 s1 = p1a + p1b + bv;
      short4v h0, h1;
#pragma unroll
      for (int jj = 0; jj < 4; jj++) {
        h0[jj] = (short)f2b(fmaxf(s0[jj], 0.0f));
        h1[jj] = (short)f2b(fmaxf(s1[jj], 0.0f));
      }
      *(short4v*)(hsb + (2 * wt) * 1024 + hswr)     = h0;
      *(short4v*)(hsb + (2 * wt + 1) * 1024 + hswr) = h1;
    }
    // w2[hb] landed (full L1 region of cover); hs published by barrier
    asm volatile("s_waitcnt vmcnt(0) lgkmcnt(0)" ::: "memory");
    __builtin_amdgcn_s_barrier();

    // ===== region B: issue stage1(hb+1); L2 (10 reads -> 16 MFMA) =====
    if (notlast) stage1(hb + 1);   // safe: A(hb) end-barrier drained all w1 reads

    {
      bf16x8 hf0 = *(const bf16x8*)(hsb + (2 * wt) * 1024 + lane * 16);
      bf16x8 hf1 = *(const bf16x8*)(hsb + (2 * wt + 1) * 1024 + lane * 16);
      __builtin_amdgcn_s_setprio(1);
#pragma unroll
      for (int ni = 0; ni < 8; ni++) {
        bf16x8 a2 = *(const bf16x8*)(w2c + (wh * 8 + ni) * 1024 + lane * 16);
        acc2[0][ni] = MFMA16(a2, hf0, acc2[0][ni]);
        acc2[1][ni] = MFMA16(a2, hf1, acc2[1][ni]);
      }
      __builtin_amdgcn_s_setprio(0);
    }
    // w1[hb+1] landed (full L2 region of cover); hs reads drained before rewrite
    if (notlast) {
      asm volatile("s_waitcnt vmcnt(0) lgkmcnt(0)" ::: "memory");
      __builtin_amdgcn_s_barrier();
    }
  }

  // ---- epilogue: + b2, vectorized scatter ----
#pragma unroll
  for (int ti = 0; ti < 2; ti++) {
    const int tok = toksp[(2 * wt + ti) * 16 + lrow];
    if (tok >= 0) {
#pragma unroll
      for (int ni = 0; ni < 8; ni++) {
        const int n0 = wh * 128 + ni * 16 + lgrp * 4;
        f32x4 bv = *(const f32x4*)(b2s + n0);
        f32x4 v = acc2[ti][ni] + bv;
        *(f32x4*)(out + (size_t)tok * DOUT + n0) = v;
      }
    }
  }
}

extern "C" void kernel_launch(void* const* d_in, const int* in_sizes, int n_in,
                              void* d_out, int out_size, void* d_ws, size_t ws_size,
                              hipStream_t stream) {
  (void)in_sizes; (void)n_in; (void)out_size; (void)ws_size;
  const float* x   = (const float*)d_in[0];
  const int*   cat = (const int*)d_in[1];
  const float* W1  = (const float*)d_in[2];
  const float* b1  = (const float*)d_in[3];
  const float* W2  = (const float*)d_in[4];
  const float* b2  = (const float*)d_in[5];
  float* out = (float*)d_out;

  char* ws = (char*)d_ws;
  int* counts    = (int*)(ws);
  int* padoff    = (int*)(ws + 128);
  int* blockhist = (int*)(ws + 4096);
  int* base      = (int*)(ws + 65536);
  int* idx       = (int*)(ws + 131072);
  short* w1b     = (short*)(ws + (1 << 20));
  short* w2b     = (short*)(ws + (1 << 20) + 8388608);

  hist_k<<<NB, 256, 0, stream>>>(cat, blockhist);
  offsets2_k<<<1, 1024, 0, stream>>>(blockhist, counts, padoff, base);
  scatter2_k<<<NB, 256, 0, stream>>>(cat, base, idx);
  conv_w1_k<<<2048, 256, 0, stream>>>(W1, w1b);
  conv_w2_k<<<2048, 256, 0, stream>>>(W2, w2b);

  const int ntiles = BB / TM + CC;   // 2064 = 8 * 258 (swizzle assumes this)
  mlp_k<<<ntiles, 256, 0, stream>>>(x, b1, b2, w1b, w2b, idx, padoff, counts, out);
}